// Round 2
// baseline (269.577 us; speedup 1.0000x reference)
//
#include <hip/hip_runtime.h>
#include <hip/hip_cooperative_groups.h>
#include <cmath>

namespace cg = cooperative_groups;

#define NQ 32
#define H 512
#define NOFF 496
#define NR4 528   // NQ + NOFF
#define NC 33     // 1 activation col + 32 jacobian cols

__device__ __forceinline__ float sigmoidf(float x) {
    return 1.0f / (1.0f + __expf(-x));
}
__device__ __forceinline__ float dot4(float4 a, float4 b) {
    return a.x * b.x + a.y * b.y + a.z * b.z + a.w * b.w;
}
__device__ __forceinline__ float4 sig4(float4 a) {
    return make_float4(sigmoidf(a.x), sigmoidf(a.y), sigmoidf(a.z), sigmoidf(a.w));
}

// One cooperative kernel; 297 blocks x 256 threads.
// Phase1: Y[k] = W2 @ Bk (Bk recomputed inline from W1/q), g2pre = Wg2@g1
// Phase2: Z[k] = W3 @ Bk(Y), gvec = Wg3@sig(g2pre+bg2)+bg3
// Phase3: U[k] = [Wd;Wo] @ Bk(Z)
// Phase4: block 0 assembles tau.
__global__ void __launch_bounds__(256, 2) fused(
    const float* __restrict__ q, const float* __restrict__ q_t, const float* __restrict__ q_tt,
    const float* __restrict__ W1, const float* __restrict__ b1,
    const float* __restrict__ W2, const float* __restrict__ b2,
    const float* __restrict__ W3, const float* __restrict__ b3,
    const float* __restrict__ Wd, const float* __restrict__ bd,
    const float* __restrict__ Wo, const float* __restrict__ bo,
    const float* __restrict__ Wg1, const float* __restrict__ bg1,
    const float* __restrict__ Wg2, const float* __restrict__ bg2,
    const float* __restrict__ Wg3, const float* __restrict__ bg3,
    float* __restrict__ Y, float* __restrict__ g2pre,
    float* __restrict__ Z, float* __restrict__ gvec,
    float* __restrict__ U, float* __restrict__ out)
{
    cg::grid_group grid = cg::this_grid();
    const int b = blockIdx.x;          // 0..296
    const int tid = threadIdx.x;
    const int lane = tid & 63, wv = tid >> 6;

    __shared__ float qs[NQ];
    // phase-4 (k5) scratch
    __shared__ float ldiag[NQ], loff[NOFF], vv[NR4];
    __shared__ float Lm[NQ][NQ + 1], Dq[NQ][NQ + 1], Fj[NQ][NQ + 1];
    __shared__ float qts[NQ], qtts[NQ], LTq[NQ], t1s[NQ], u2[NQ];

    if (tid < NQ) qs[tid] = q[tid];
    __syncthreads();

    // ---------------- Phase 1 ----------------
    if (b < 272) {
        const int k = b >> 3, rb = b & 7;
        const float* Wf = (k == NC) ? Wg1 : W1;
        const float* bf = (k == NC) ? bg1 : b1;
        float4 breg[2];
        #pragma unroll
        for (int t = 0; t < 2; ++t) {
            float rr[4];
            #pragma unroll
            for (int u = 0; u < 4; ++u) {
                int j = 4 * (lane + t * 64) + u;
                const float4* w = (const float4*)(Wf + j * NQ);
                float acc = 0.f;
                #pragma unroll
                for (int c = 0; c < 8; ++c) {
                    float4 wc = w[c];
                    acc += wc.x * qs[4*c] + wc.y * qs[4*c+1] + wc.z * qs[4*c+2] + wc.w * qs[4*c+3];
                }
                float h = sigmoidf(acc + bf[j]);
                rr[u] = (k == 0 || k == NC) ? h : h * (1.f - h) * Wf[j * NQ + (k - 1)];
            }
            breg[t] = make_float4(rr[0], rr[1], rr[2], rr[3]);
        }
        const float4* Mv = (const float4*)((k == NC) ? Wg2 : W2);
        float* outp = (k == NC) ? g2pre : (Y + k * H);
        int r0 = rb * 64 + wv * 16;
        #pragma unroll 4
        for (int i = 0; i < 16; ++i) {
            int r = r0 + i;
            const float4* wr = Mv + (size_t)r * (H / 4);
            float acc = dot4(wr[lane], breg[0]) + dot4(wr[lane + 64], breg[1]);
            #pragma unroll
            for (int m = 32; m > 0; m >>= 1) acc += __shfl_xor(acc, m, 64);
            if (lane == 0) outp[r] = acc;
        }
    }
    grid.sync();

    // ---------------- Phase 2 ----------------
    if (b < 272) {
        const int k = b >> 3, rb = b & 7;
        if (k == NC) {
            if (rb == 0) {
                const float4* Gp = (const float4*)g2pre;
                const float4* Bg = (const float4*)bg2;
                float4 breg[2];
                #pragma unroll
                for (int t = 0; t < 2; ++t) {
                    float4 a = Gp[lane + t * 64], bb = Bg[lane + t * 64];
                    breg[t] = sig4(make_float4(a.x + bb.x, a.y + bb.y, a.z + bb.z, a.w + bb.w));
                }
                #pragma unroll
                for (int i = 0; i < 8; ++i) {
                    int r = wv * 8 + i;
                    const float4* wr = (const float4*)Wg3 + (size_t)r * (H / 4);
                    float acc = dot4(wr[lane], breg[0]) + dot4(wr[lane + 64], breg[1]);
                    #pragma unroll
                    for (int m = 32; m > 0; m >>= 1) acc += __shfl_xor(acc, m, 64);
                    if (lane == 0) gvec[r] = acc + bg3[r];
                }
            }
        } else {
            const float4* Y0 = (const float4*)Y;
            const float4* Yk = (const float4*)(Y + k * H);
            const float4* B2 = (const float4*)b2;
            float4 breg[2];
            #pragma unroll
            for (int t = 0; t < 2; ++t) {
                float4 y0 = Y0[lane + t * 64], bb = B2[lane + t * 64];
                float4 h = sig4(make_float4(y0.x + bb.x, y0.y + bb.y, y0.z + bb.z, y0.w + bb.w));
                if (k == 0) breg[t] = h;
                else {
                    float4 yk = Yk[lane + t * 64];
                    breg[t] = make_float4(h.x * (1.f - h.x) * yk.x, h.y * (1.f - h.y) * yk.y,
                                          h.z * (1.f - h.z) * yk.z, h.w * (1.f - h.w) * yk.w);
                }
            }
            float* outp = Z + k * H;
            int r0 = rb * 64 + wv * 16;
            #pragma unroll 4
            for (int i = 0; i < 16; ++i) {
                int r = r0 + i;
                const float4* wr = (const float4*)W3 + (size_t)r * (H / 4);
                float acc = dot4(wr[lane], breg[0]) + dot4(wr[lane + 64], breg[1]);
                #pragma unroll
                for (int m = 32; m > 0; m >>= 1) acc += __shfl_xor(acc, m, 64);
                if (lane == 0) outp[r] = acc;
            }
        }
    }
    grid.sync();

    // ---------------- Phase 3 ----------------
    {
        const int k = b / 9, rb = b % 9;   // 33 x 9 = 297
        const float4* Z0 = (const float4*)Z;
        const float4* Zk = (const float4*)(Z + k * H);
        const float4* B3 = (const float4*)b3;
        float4 breg[2];
        #pragma unroll
        for (int t = 0; t < 2; ++t) {
            float4 z0 = Z0[lane + t * 64], bb = B3[lane + t * 64];
            float4 h = sig4(make_float4(z0.x + bb.x, z0.y + bb.y, z0.z + bb.z, z0.w + bb.w));
            if (k == 0) breg[t] = h;
            else {
                float4 zk = Zk[lane + t * 64];
                breg[t] = make_float4(h.x * (1.f - h.x) * zk.x, h.y * (1.f - h.y) * zk.y,
                                      h.z * (1.f - h.z) * zk.z, h.w * (1.f - h.w) * zk.w);
            }
        }
        int r0 = rb * 64 + wv * 16;
        for (int i = 0; i < 16; ++i) {
            int r = r0 + i;
            if (r >= NR4) break;
            const float4* wr = (r < NQ) ? ((const float4*)Wd + (size_t)r * (H / 4))
                                        : ((const float4*)Wo + (size_t)(r - NQ) * (H / 4));
            float acc = dot4(wr[lane], breg[0]) + dot4(wr[lane + 64], breg[1]);
            #pragma unroll
            for (int m = 32; m > 0; m >>= 1) acc += __shfl_xor(acc, m, 64);
            if (lane == 0) U[k * NR4 + r] = acc;
        }
    }
    grid.sync();

    // ---------------- Phase 4 (block 0 only) ----------------
    if (b == 0) {
        if (tid < NQ) {
            ldiag[tid] = __expf(U[tid] + bd[tid]);
            qts[tid]  = q_t[tid];
            qtts[tid] = q_tt[tid];
        }
        for (int r = tid; r < NOFF; r += 256)
            loff[r] = U[NQ + r] + bo[r];
        __syncthreads();
        for (int m = tid; m < NR4; m += 256) {
            float acc = 0.f;
            #pragma unroll
            for (int kk = 0; kk < NQ; ++kk)
                acc += U[(kk + 1) * NR4 + m] * qts[kk];
            vv[m] = (m < NQ) ? ldiag[m] * acc : acc;
        }
        for (int p = tid; p < NQ * NQ; p += 256) {
            int i = p >> 5, j = p & 31;
            Lm[i][j] = (i == j) ? ldiag[i]
                     : (j < i ? loff[i * (i - 1) / 2 + j] : 0.f);
        }
        for (int p = tid; p < NQ * NQ; p += 256) {
            int j = p >> 5, k = p & 31;
            const float* Uc = U + (k + 1) * NR4;
            float acc = qts[j] * ldiag[j] * Uc[j];
            for (int i = j + 1; i < NQ; ++i)
                acc += qts[i] * Uc[NQ + i * (i - 1) / 2 + j];
            Fj[j][k] = acc;
        }
        __syncthreads();
        for (int p = tid; p < NQ * NQ; p += 256) {
            int i = p >> 5, j = p & 31;
            Dq[i][j] = (i == j) ? vv[i]
                     : (j < i ? vv[NQ + i * (i - 1) / 2 + j] : 0.f);
        }
        if (tid < NQ) {
            int kcol = tid;
            float a = 0.f, bsum = 0.f;
            #pragma unroll
            for (int j = 0; j < NQ; ++j) {
                a    += Lm[j][kcol] * qts[j];
                bsum += Lm[j][kcol] * qtts[j];
            }
            LTq[kcol] = a;
            t1s[kcol] = bsum;
        }
        __syncthreads();
        if (tid < NQ) {
            int kcol = tid;
            float a = 0.f;
            #pragma unroll
            for (int j = 0; j < NQ; ++j) a += Dq[j][kcol] * qts[j];
            u2[kcol] = a;
        }
        __syncthreads();
        if (tid < NQ) {
            int i = tid;
            float c1 = 0.f, c2 = 0.f, c3 = 0.f, c4 = 0.f;
            #pragma unroll
            for (int kk = 0; kk < NQ; ++kk) {
                c1 += Lm[i][kk] * t1s[kk];
                c2 += Lm[i][kk] * u2[kk];
                c3 += Dq[i][kk] * LTq[kk];
                c4 += Fj[i][kk] * LTq[kk];
            }
            out[i] = c1 + c2 + 0.5f * c3 - 0.5f * c4 + gvec[i];
        }
    }
}

extern "C" void kernel_launch(void* const* d_in, const int* in_sizes, int n_in,
                              void* d_out, int out_size, void* d_ws, size_t ws_size,
                              hipStream_t stream) {
    const float* q    = (const float*)d_in[0];
    const float* q_t  = (const float*)d_in[1];
    const float* q_tt = (const float*)d_in[2];
    const float* W1   = (const float*)d_in[3];
    const float* b1   = (const float*)d_in[4];
    const float* W2   = (const float*)d_in[5];
    const float* b2   = (const float*)d_in[6];
    const float* W3   = (const float*)d_in[7];
    const float* b3   = (const float*)d_in[8];
    const float* Wd   = (const float*)d_in[9];
    const float* bd   = (const float*)d_in[10];
    const float* Wo   = (const float*)d_in[11];
    const float* bo   = (const float*)d_in[12];
    const float* Wg1  = (const float*)d_in[13];
    const float* bg1  = (const float*)d_in[14];
    const float* Wg2  = (const float*)d_in[15];
    const float* bg2  = (const float*)d_in[16];
    const float* Wg3  = (const float*)d_in[17];
    const float* bg3  = (const float*)d_in[18];

    float* ws = (float*)d_ws;
    float* Y     = ws;                 // 33*512 = 16896 (col-major)
    float* g2pre = ws + 16896;         // 512
    float* Z     = ws + 17408;         // 33*512 = 16896
    float* gvec  = ws + 34304;         // 32
    float* U     = ws + 34336;         // 33*528 = 17424
    float* out   = (float*)d_out;

    void* args[] = {
        (void*)&q, (void*)&q_t, (void*)&q_tt,
        (void*)&W1, (void*)&b1, (void*)&W2, (void*)&b2, (void*)&W3, (void*)&b3,
        (void*)&Wd, (void*)&bd, (void*)&Wo, (void*)&bo,
        (void*)&Wg1, (void*)&bg1, (void*)&Wg2, (void*)&bg2, (void*)&Wg3, (void*)&bg3,
        (void*)&Y, (void*)&g2pre, (void*)&Z, (void*)&gvec, (void*)&U, (void*)&out
    };
    hipLaunchCooperativeKernel((void*)fused, dim3(297), dim3(256), args, 0, stream);
}

// Round 3
// 192.512 us; speedup vs baseline: 1.4003x; 1.4003x over previous
//
#include <hip/hip_runtime.h>
#include <cmath>

#define NQ 32
#define H 512
#define NOFF 496
#define NR4 528   // NQ + NOFF
#define NBLK 34   // 33 column blocks (k=0 activation, k=1..32 jacobian) + 1 g-net block

__device__ __forceinline__ float sigmoidf(float x) {
    return 1.0f / (1.0f + __expf(-x));
}
__device__ __forceinline__ float dot4(float4 a, float4 b) {
    return a.x * b.x + a.y * b.y + a.z * b.z + a.w * b.w;
}
__device__ __forceinline__ float ldagent(const float* p) {
    return __hip_atomic_load(p, __ATOMIC_RELAXED, __HIP_MEMORY_SCOPE_AGENT);
}

// One block per column; no grid sync. Last block to finish (fan-in atomic)
// performs the triangular assembly.
__global__ void __launch_bounds__(1024, 1) fused(
    const float* __restrict__ q, const float* __restrict__ q_t, const float* __restrict__ q_tt,
    const float* __restrict__ W1, const float* __restrict__ b1,
    const float* __restrict__ W2, const float* __restrict__ b2,
    const float* __restrict__ W3, const float* __restrict__ b3,
    const float* __restrict__ Wd, const float* __restrict__ bd,
    const float* __restrict__ Wo, const float* __restrict__ bo,
    const float* __restrict__ Wg1, const float* __restrict__ bg1,
    const float* __restrict__ Wg2, const float* __restrict__ bg2,
    const float* __restrict__ Wg3, const float* __restrict__ bg3,
    float* __restrict__ U, float* __restrict__ gvec,
    unsigned* __restrict__ done, float* __restrict__ out)
{
    const int k = blockIdx.x;          // 0..33
    const int tid = threadIdx.x;       // 0..1023 (16 waves)
    const int lane = tid & 63, wv = tid >> 6;
    const bool isg = (k == NBLK - 1);

    __shared__ float qs[NQ];
    __shared__ float hA[H], bB[H];     // layer-1 / layer-3 buffers
    __shared__ float hA2[H], bB2[H];   // layer-2 buffers
    // phase-4 scratch
    __shared__ float ldiag[NQ], loff[NOFF], vv[NR4];
    __shared__ float Lm[NQ][NQ + 1], Dq[NQ][NQ + 1], Fj[NQ][NQ + 1];
    __shared__ float qts[NQ], qtts[NQ], LTq[NQ], t1s[NQ], u2[NQ];
    __shared__ int amLast;

    if (tid < NQ) qs[tid] = q[tid];
    __syncthreads();

    // ---- Layer 1: h1 / g1 and B1 (column k-1 of s1*W1) ----
    if (tid < H) {
        const float* Wf = isg ? Wg1 : W1;
        const float* bf = isg ? bg1 : b1;
        const float4* wr = (const float4*)(Wf + tid * NQ);
        float acc = 0.f;
        #pragma unroll
        for (int c = 0; c < 8; ++c) {
            float4 w = wr[c];
            acc += w.x * qs[4*c] + w.y * qs[4*c+1] + w.z * qs[4*c+2] + w.w * qs[4*c+3];
        }
        float h = sigmoidf(acc + bf[tid]);
        hA[tid] = h;
        bB[tid] = (k == 0 || isg) ? h : h * (1.f - h) * Wf[tid * NQ + (k - 1)];
    }
    __syncthreads();

    // ---- Layer 2: h2 = sig(W2@h1+b2) and Yk = W2@B1 (shared row loads) ----
    {
        const float4* h4 = (const float4*)hA;
        const float4* b4 = (const float4*)bB;
        float4 hreg0 = h4[lane], hreg1 = h4[lane + 64];
        float4 breg0 = b4[lane], breg1 = b4[lane + 64];
        if (!isg) {
            #pragma unroll 4
            for (int i = 0; i < 32; ++i) {
                int r = wv * 32 + i;
                const float4* wr = (const float4*)W2 + (size_t)r * (H / 4);
                float4 wa = wr[lane], wb = wr[lane + 64];
                float aH = dot4(wa, hreg0) + dot4(wb, hreg1);
                float aB = dot4(wa, breg0) + dot4(wb, breg1);
                #pragma unroll
                for (int m = 32; m > 0; m >>= 1) {
                    aH += __shfl_xor(aH, m, 64);
                    aB += __shfl_xor(aB, m, 64);
                }
                if (lane == 0) {
                    float h2 = sigmoidf(aH + b2[r]);
                    hA2[r] = h2;
                    bB2[r] = (k == 0) ? h2 : h2 * (1.f - h2) * aB;
                }
            }
        } else {
            #pragma unroll 4
            for (int i = 0; i < 32; ++i) {
                int r = wv * 32 + i;
                const float4* wr = (const float4*)Wg2 + (size_t)r * (H / 4);
                float acc = dot4(wr[lane], hreg0) + dot4(wr[lane + 64], hreg1);
                #pragma unroll
                for (int m = 32; m > 0; m >>= 1) acc += __shfl_xor(acc, m, 64);
                if (lane == 0) hA2[r] = sigmoidf(acc + bg2[r]);
            }
        }
    }
    __syncthreads();

    // ---- Layer 3 ----
    {
        const float4* h4 = (const float4*)hA2;
        const float4* b4 = (const float4*)bB2;
        float4 hreg0 = h4[lane], hreg1 = h4[lane + 64];
        float4 breg0 = b4[lane], breg1 = b4[lane + 64];
        if (!isg) {
            #pragma unroll 4
            for (int i = 0; i < 32; ++i) {
                int r = wv * 32 + i;
                const float4* wr = (const float4*)W3 + (size_t)r * (H / 4);
                float4 wa = wr[lane], wb = wr[lane + 64];
                float aH = dot4(wa, hreg0) + dot4(wb, hreg1);
                float aB = dot4(wa, breg0) + dot4(wb, breg1);
                #pragma unroll
                for (int m = 32; m > 0; m >>= 1) {
                    aH += __shfl_xor(aH, m, 64);
                    aB += __shfl_xor(aB, m, 64);
                }
                if (lane == 0) {
                    float h3 = sigmoidf(aH + b3[r]);
                    hA[r] = h3;
                    bB[r] = (k == 0) ? h3 : h3 * (1.f - h3) * aB;
                }
            }
        } else {
            // gvec = Wg3 @ g2 + bg3  (32 rows, 2 per wave)
            #pragma unroll
            for (int i = 0; i < 2; ++i) {
                int r = wv * 2 + i;
                const float4* wr = (const float4*)Wg3 + (size_t)r * (H / 4);
                float acc = dot4(wr[lane], hreg0) + dot4(wr[lane + 64], hreg1);
                #pragma unroll
                for (int m = 32; m > 0; m >>= 1) acc += __shfl_xor(acc, m, 64);
                if (lane == 0) gvec[r] = acc + bg3[r];
            }
        }
    }
    __syncthreads();

    // ---- Layer 4: U[:,k] = [Wd;Wo] @ B3 (528 rows, 33 per wave) ----
    if (!isg) {
        const float4* h4 = (const float4*)bB;
        float4 breg0 = h4[lane], breg1 = h4[lane + 64];
        #pragma unroll 3
        for (int i = 0; i < 33; ++i) {
            int r = i * 16 + wv;       // 0..527
            const float4* wr = (r < NQ) ? ((const float4*)Wd + (size_t)r * (H / 4))
                                        : ((const float4*)Wo + (size_t)(r - NQ) * (H / 4));
            float acc = dot4(wr[lane], breg0) + dot4(wr[lane + 64], breg1);
            #pragma unroll
            for (int m = 32; m > 0; m >>= 1) acc += __shfl_xor(acc, m, 64);
            if (lane == 0) U[k * NR4 + r] = acc;
        }
    }

    // ---- Fan-in: last block to arrive does the assembly ----
    __threadfence();
    __syncthreads();
    if (tid == 0) {
        unsigned old = atomicAdd(done, 1u);
        amLast = (old == NBLK - 1) ? 1 : 0;
    }
    __syncthreads();
    if (!amLast) return;
    __threadfence();

    // ---- Phase 4: triangular assembly (one block, 1024 threads) ----
    if (tid < NQ) {
        ldiag[tid] = __expf(ldagent(&U[tid]) + bd[tid]);
        qts[tid]  = q_t[tid];
        qtts[tid] = q_tt[tid];
    }
    for (int r = tid; r < NOFF; r += 1024)
        loff[r] = ldagent(&U[NQ + r]) + bo[r];
    __syncthreads();
    for (int m = tid; m < NR4; m += 1024) {
        float acc = 0.f;
        #pragma unroll
        for (int kk = 0; kk < NQ; ++kk)
            acc += ldagent(&U[(kk + 1) * NR4 + m]) * qts[kk];
        vv[m] = (m < NQ) ? ldiag[m] * acc : acc;
    }
    for (int p = tid; p < NQ * NQ; p += 1024) {
        int i = p >> 5, j = p & 31;
        Lm[i][j] = (i == j) ? ldiag[i]
                 : (j < i ? loff[i * (i - 1) / 2 + j] : 0.f);
    }
    for (int p = tid; p < NQ * NQ; p += 1024) {
        int j = p >> 5, kk = p & 31;
        const float* Uc = U + (kk + 1) * NR4;
        float acc = qts[j] * ldiag[j] * ldagent(&Uc[j]);
        for (int i = j + 1; i < NQ; ++i)
            acc += qts[i] * ldagent(&Uc[NQ + i * (i - 1) / 2 + j]);
        Fj[j][kk] = acc;
    }
    __syncthreads();
    for (int p = tid; p < NQ * NQ; p += 1024) {
        int i = p >> 5, j = p & 31;
        Dq[i][j] = (i == j) ? vv[i]
                 : (j < i ? vv[NQ + i * (i - 1) / 2 + j] : 0.f);
    }
    if (tid < NQ) {
        int kcol = tid;
        float a = 0.f, bsum = 0.f;
        #pragma unroll
        for (int j = 0; j < NQ; ++j) {
            a    += Lm[j][kcol] * qts[j];
            bsum += Lm[j][kcol] * qtts[j];
        }
        LTq[kcol] = a;
        t1s[kcol] = bsum;
    }
    __syncthreads();
    if (tid < NQ) {
        int kcol = tid;
        float a = 0.f;
        #pragma unroll
        for (int j = 0; j < NQ; ++j) a += Dq[j][kcol] * qts[j];
        u2[kcol] = a;
    }
    __syncthreads();
    if (tid < NQ) {
        int i = tid;
        float c1 = 0.f, c2 = 0.f, c3 = 0.f, c4 = 0.f;
        #pragma unroll
        for (int kk = 0; kk < NQ; ++kk) {
            c1 += Lm[i][kk] * t1s[kk];
            c2 += Lm[i][kk] * u2[kk];
            c3 += Dq[i][kk] * LTq[kk];
            c4 += Fj[i][kk] * LTq[kk];
        }
        out[i] = c1 + c2 + 0.5f * c3 - 0.5f * c4 + ldagent(&gvec[i]);
    }
}

extern "C" void kernel_launch(void* const* d_in, const int* in_sizes, int n_in,
                              void* d_out, int out_size, void* d_ws, size_t ws_size,
                              hipStream_t stream) {
    const float* q    = (const float*)d_in[0];
    const float* q_t  = (const float*)d_in[1];
    const float* q_tt = (const float*)d_in[2];
    const float* W1   = (const float*)d_in[3];
    const float* b1   = (const float*)d_in[4];
    const float* W2   = (const float*)d_in[5];
    const float* b2   = (const float*)d_in[6];
    const float* W3   = (const float*)d_in[7];
    const float* b3   = (const float*)d_in[8];
    const float* Wd   = (const float*)d_in[9];
    const float* bd   = (const float*)d_in[10];
    const float* Wo   = (const float*)d_in[11];
    const float* bo   = (const float*)d_in[12];
    const float* Wg1  = (const float*)d_in[13];
    const float* bg1  = (const float*)d_in[14];
    const float* Wg2  = (const float*)d_in[15];
    const float* bg2  = (const float*)d_in[16];
    const float* Wg3  = (const float*)d_in[17];
    const float* bg3  = (const float*)d_in[18];

    float* ws = (float*)d_ws;
    float* U       = ws;                   // 33*528 = 17424 (col-major)
    float* gvec    = ws + 17424;           // 32
    unsigned* done = (unsigned*)(ws + 17456);
    float* out     = (float*)d_out;

    hipMemsetAsync(done, 0, sizeof(unsigned), stream);
    hipLaunchKernelGGL(fused, dim3(NBLK), dim3(1024), 0, stream,
                       q, q_t, q_tt, W1, b1, W2, b2, W3, b3,
                       Wd, bd, Wo, bo, Wg1, bg1, Wg2, bg2, Wg3, bg3,
                       U, gvec, done, out);
}